// Round 6
// baseline (3314.076 us; speedup 1.0000x reference)
//
#include <hip/hip_runtime.h>
#include <hip/hip_bf16.h>

#define Nn 50000
#define Ee 1600000
#define Ff 64
#define Rr 5
#define Bb 4
#define Ll 4
#define Kk 2048
#define Mseg (Rr*Nn)   // 250000 segments, rel-major: seg = r*Nn + dst
#define NT ((Nn+63)/64)  // 782 node tiles
#define SVP 68

__global__ __launch_bounds__(256) void k_inv_init(int* __restrict__ inv){
  int i = blockIdx.x*256+threadIdx.x;
  if (i < Nn) inv[i] = -1;
}

__global__ __launch_bounds__(256) void k_inv_set(const int* __restrict__ tidx, int* __restrict__ inv,
                                                 int* __restrict__ tflag){
  int k = blockIdx.x*256+threadIdx.x;
  if (k < Kk){
    int n = tidx[k];
    inv[n] = k;
    tflag[n >> 6] = 1;   // benign race
  }
}

__global__ __launch_bounds__(256) void k_cnt2(const int* __restrict__ ei, const int* __restrict__ et,
                                              int* __restrict__ cnt2){
  int e = blockIdx.x*256+threadIdx.x;
  if (e < Ee){
    int dst = ei[Ee + e];
    int r = et[e];
    atomicAdd(&cnt2[r*Nn + dst], 1);
  }
}

__global__ __launch_bounds__(256) void k_scan_blk(const int* __restrict__ cnt2, int* __restrict__ part,
                                                  int* __restrict__ bsum){
  __shared__ int s[256];
  int t = threadIdx.x; int idx = blockIdx.x*256+t;
  int v = (idx < Mseg) ? cnt2[idx] : 0;
  s[t] = v; __syncthreads();
  #pragma unroll
  for (int off=1; off<256; off<<=1){
    int x = (t>=off) ? s[t-off] : 0;
    __syncthreads();
    s[t] += x;
    __syncthreads();
  }
  if (idx < Mseg) part[idx] = s[t] - v;
  if (t == 255) bsum[blockIdx.x] = s[255];
}

__global__ __launch_bounds__(1024) void k_scan_top(int* __restrict__ bsum, int nb){
  __shared__ int s[1024];
  int t = threadIdx.x;
  int v = (t < nb) ? bsum[t] : 0;
  s[t] = v; __syncthreads();
  #pragma unroll
  for (int off=1; off<1024; off<<=1){
    int x = (t>=off) ? s[t-off] : 0;
    __syncthreads();
    s[t] += x;
    __syncthreads();
  }
  if (t < nb) bsum[t] = s[t] - v;
}

__global__ __launch_bounds__(256) void k_scan_add(const int* __restrict__ part, const int* __restrict__ bsum,
                                                  int* __restrict__ rowptr){
  int idx = blockIdx.x*256+threadIdx.x;
  if (idx < Mseg) rowptr[idx] = part[idx] + bsum[idx>>8];
  if (idx == 0) rowptr[Mseg] = Ee;
}

// rel-major CSR; entry = src | dst<<16 (both < 65536)
__global__ __launch_bounds__(256) void k_place(const int* __restrict__ ei, const int* __restrict__ et,
                                               const int* __restrict__ rowptr, int* __restrict__ fill,
                                               unsigned* __restrict__ edg){
  int e = blockIdx.x*256+threadIdx.x;
  if (e < Ee){
    int src = ei[e];
    int dst = ei[Ee + e];
    int r = et[e];
    int seg = r*Nn + dst;
    int pos = rowptr[seg] + atomicAdd(&fill[seg], 1);
    edg[pos] = (unsigned)src | ((unsigned)dst << 16);
  }
}

// Wall: 384x64 fp32. rows 0..319 = W_r, rows 320..383 = root.
__global__ __launch_bounds__(256) void k_wall(const float* __restrict__ bases, const float* __restrict__ comps,
                                              const float* __restrict__ roots, float* __restrict__ Wall){
  int idx = blockIdx.x*256+threadIdx.x;
  if (idx >= 384*64) return;
  int o = idx & 63, row = idx >> 6;
  float s;
  if (row < 320){
    int r = row >> 6, i = row & 63;
    s = 0.f;
    #pragma unroll
    for (int b=0;b<Bb;b++)
      s += comps[r*Bb+b] * bases[(b*Ff + i)*Ff + o];
  } else {
    int i = row - 320;
    s = roots[i*Ff + o];
  }
  Wall[idx] = s;
}

// Fused RGCN layer. Block = 64 dst nodes x 64 outputs. Per rel c:
//   gather: waves each grab a 64-edge window with ONE coalesced load, then a
//   fully-unrolled readlane-broadcast loop issues independent h-row loads and
//   ds_add accumulations (sentinel row 64 absorbs out-of-window lanes).
//   Then mean-divide, then 4x4 register-blocked matmul vs W_c.
__global__ __launch_bounds__(256) void k_rgcn(const unsigned* __restrict__ edg,
    const int* __restrict__ rowptr, const float* __restrict__ Wall,
    const float* __restrict__ h, const float* __restrict__ bias,
    float* __restrict__ hn, const int* __restrict__ inv, float* __restrict__ sel,
    int layer, const int* __restrict__ tflag)
{
  if (layer == Ll-1 && tflag[blockIdx.x] == 0) return;   // last layer: only target tiles
  __shared__ __align__(16) float sW[64*64];
  __shared__ __align__(16) float sV[65*SVP];             // row 64 = scrap (sentinel)
  int t = threadIdx.x;
  int n0 = blockIdx.x*64;
  int nlim = Nn - n0; if (nlim > 64) nlim = 64;
  int wv = t >> 6, f = t & 63;
  int oq = (t & 15)*4, nq = (t >> 4)*4;
  float4 acc[4];
  #pragma unroll
  for (int j=0;j<4;j++) acc[j] = make_float4(0.f,0.f,0.f,0.f);

  for (int c=0;c<6;c++){
    // stage W_c (+ prep sV)
    #pragma unroll
    for (int idx=t; idx<1024; idx+=256)
      *(float4*)&sW[idx*4] = *(const float4*)&Wall[c*4096 + idx*4];
    if (c < 5){
      #pragma unroll
      for (int idx=t; idx<1024; idx+=256){
        int nl = idx>>4, iq = (idx&15)*4;
        *(float4*)&sV[nl*SVP + iq] = make_float4(0.f,0.f,0.f,0.f);
      }
      __syncthreads();
      int segbase = c*Nn + n0;
      int s = rowptr[segbase];
      int e = rowptr[segbase + nlim];
      for (int w = s + wv*64; w < e; w += 256){
        int nval = e - w; nval = (nval > 64) ? 64 : nval;
        int li = (f < nval) ? f : (nval - 1);
        unsigned u = edg[w + li];
        #pragma unroll
        for (int j=0;j<64;j++){
          unsigned uu = __shfl(u, j, 64);
          int row = (j < nval) ? (int)(uu >> 16) - n0 : 64;
          float v = h[(size_t)(uu & 0xffffu)*64 + f];
          atomicAdd(&sV[row*SVP + f], v);
        }
      }
      __syncthreads();
      // mean divide
      for (int idx=t; idx<4096; idx+=256){
        int nl = idx>>6, i = idx&63;
        if (nl < nlim){
          int cc = rowptr[segbase+nl+1] - rowptr[segbase+nl];
          if (cc > 1) sV[nl*SVP+i] *= (1.0f/(float)cc);
        }
      }
      __syncthreads();
    } else {
      // root term: sV = h tile
      #pragma unroll
      for (int idx=t; idx<1024; idx+=256){
        int nl = idx>>4, iq = (idx&15)*4;
        float4 v = make_float4(0.f,0.f,0.f,0.f);
        if (nl < nlim) v = *(const float4*)&h[(size_t)(n0 + nl)*64 + iq];
        *(float4*)&sV[nl*SVP + iq] = v;
      }
      __syncthreads();
    }
    // 4x4 register-blocked matmul
    #pragma unroll
    for (int i=0;i<64;i+=4){
      float4 v0 = *(const float4*)&sV[(nq+0)*SVP + i];
      float4 v1 = *(const float4*)&sV[(nq+1)*SVP + i];
      float4 v2 = *(const float4*)&sV[(nq+2)*SVP + i];
      float4 v3 = *(const float4*)&sV[(nq+3)*SVP + i];
      float4 w0 = *(const float4*)&sW[(i+0)*64 + oq];
      float4 w1 = *(const float4*)&sW[(i+1)*64 + oq];
      float4 w2 = *(const float4*)&sW[(i+2)*64 + oq];
      float4 w3 = *(const float4*)&sW[(i+3)*64 + oq];
      #define FMA4(A, V) \
        A.x += V.x*w0.x + V.y*w1.x + V.z*w2.x + V.w*w3.x; \
        A.y += V.x*w0.y + V.y*w1.y + V.z*w2.y + V.w*w3.y; \
        A.z += V.x*w0.z + V.y*w1.z + V.z*w2.z + V.w*w3.z; \
        A.w += V.x*w0.w + V.y*w1.w + V.z*w2.w + V.w*w3.w;
      FMA4(acc[0], v0)
      FMA4(acc[1], v1)
      FMA4(acc[2], v2)
      FMA4(acc[3], v3)
      #undef FMA4
    }
    __syncthreads();
  }

  float4 bb = *(const float4*)&bias[oq];
  #pragma unroll
  for (int j=0;j<4;j++){
    int n = n0 + nq + j;
    if (n < Nn){
      float4 r;
      r.x = tanhf(acc[j].x + bb.x);
      r.y = tanhf(acc[j].y + bb.y);
      r.z = tanhf(acc[j].z + bb.z);
      r.w = tanhf(acc[j].w + bb.w);
      if (layer != Ll-1) *(float4*)&hn[(size_t)n*64 + oq] = r;
      int k = inv[n];
      if (k >= 0) *(float4*)&sel[(size_t)k*256 + layer*64 + oq] = r;
    }
  }
}

__global__ __launch_bounds__(256) void k_w1eff(const float* __restrict__ w1, float* __restrict__ w1e){
  int idx = blockIdx.x*256+threadIdx.x;
  if (idx < 256*128){
    int i = idx >> 7, j = idx & 127;
    w1e[idx] = w1[i*128 + j] + w1[(i+256)*128 + j];
  }
}

__global__ __launch_bounds__(128) void k_mlp(const float* __restrict__ sel, const float* __restrict__ w1e,
    const float* __restrict__ b1, const float* __restrict__ w2, const float* __restrict__ b2,
    float* __restrict__ out)
{
  __shared__ float sfeat[256];
  __shared__ float partial[2];
  int k = blockIdx.x, j = threadIdx.x;
  for (int idx=j; idx<256; idx+=128) sfeat[idx] = sel[(size_t)k*256 + idx];
  __syncthreads();
  float a = b1[j];
  for (int i=0;i<256;i++) a += sfeat[i] * w1e[i*128 + j];
  a = fmaxf(a, 0.f);
  float v = a * w2[j];
  #pragma unroll
  for (int off=32; off>0; off>>=1) v += __shfl_down(v, off, 64);
  if ((j & 63) == 0) partial[j>>6] = v;
  __syncthreads();
  if (j == 0) out[k] = partial[0] + partial[1] + b2[0];
}

extern "C" void kernel_launch(void* const* d_in, const int* in_sizes, int n_in,
                              void* d_out, int out_size, void* d_ws, size_t ws_size,
                              hipStream_t stream){
  const float* x     = (const float*)d_in[0];
  const int*  ei     = (const int*)d_in[1];
  const int*  et     = (const int*)d_in[2];
  const int*  tidx   = (const int*)d_in[3];
  const float* bases = (const float*)d_in[4];
  const float* comps = (const float*)d_in[5];
  const float* roots = (const float*)d_in[6];
  const float* biases= (const float*)d_in[7];
  const float* w1    = (const float*)d_in[8];
  const float* b1    = (const float*)d_in[9];
  const float* w2    = (const float*)d_in[10];
  const float* b2    = (const float*)d_in[11];
  float* out = (float*)d_out;

  char* wsp = (char*)d_ws;
  size_t off = 0;
  auto alloc = [&](size_t bytes)->void*{ void* p = wsp + off; off += (bytes + 255) & ~size_t(255); return p; };
  float*    h0    = (float*)alloc(sizeof(float)*(size_t)Nn*Ff);   // 12.8 MB
  float*    h1    = (float*)alloc(sizeof(float)*(size_t)Nn*Ff);   // 12.8 MB
  int*      cnt2  = (int*)  alloc(sizeof(int)*(Mseg));
  int*      part  = (int*)  alloc(sizeof(int)*(Mseg));
  int*      bsum  = (int*)  alloc(sizeof(int)*1024);
  int*      rowptr= (int*)  alloc(sizeof(int)*(Mseg+1));
  int*      fill  = (int*)  alloc(sizeof(int)*(Mseg));
  unsigned* edg   = (unsigned*)alloc(sizeof(unsigned)*(size_t)Ee); // 6.4 MB
  float*    Wall  = (float*)alloc(sizeof(float)*384*64);
  float*    sel   = (float*)alloc(sizeof(float)*(size_t)Kk*256);
  float*    w1e   = (float*)alloc(sizeof(float)*256*128);
  int*      inv   = (int*)  alloc(sizeof(int)*(size_t)Nn);
  int*      tflag = (int*)  alloc(sizeof(int)*NT);
  (void)ws_size;

  const int NB = (Mseg + 255)/256;   // 977 scan blocks

  hipMemsetAsync(cnt2, 0, sizeof(int)*Mseg, stream);
  hipMemsetAsync(fill, 0, sizeof(int)*Mseg, stream);
  hipMemsetAsync(tflag, 0, sizeof(int)*NT, stream);
  k_inv_init<<<(Nn+255)/256, 256, 0, stream>>>(inv);
  k_inv_set<<<(Kk+255)/256, 256, 0, stream>>>(tidx, inv, tflag);
  k_w1eff<<<(256*128+255)/256, 256, 0, stream>>>(w1, w1e);
  k_cnt2<<<(Ee+255)/256, 256, 0, stream>>>(ei, et, cnt2);
  k_scan_blk<<<NB, 256, 0, stream>>>(cnt2, part, bsum);
  k_scan_top<<<1, 1024, 0, stream>>>(bsum, NB);
  k_scan_add<<<NB, 256, 0, stream>>>(part, bsum, rowptr);
  k_place<<<(Ee+255)/256, 256, 0, stream>>>(ei, et, rowptr, fill, edg);

  const float* hc = x;
  float* hn = h0;
  for (int l=0;l<Ll;l++){
    k_wall<<<(384*64+255)/256, 256, 0, stream>>>(bases + (size_t)l*Bb*Ff*Ff, comps + (size_t)l*Rr*Bb,
                                                 roots + (size_t)l*Ff*Ff, Wall);
    k_rgcn<<<NT, 256, 0, stream>>>(edg, rowptr, Wall, hc, biases + (size_t)l*Ff, hn, inv, sel, l, tflag);
    hc = hn;
    hn = (hn == h0) ? h1 : h0;
  }
  k_mlp<<<Kk, 128, 0, stream>>>(sel, w1e, b1, w2, b2, out);
}

// Round 7
// 807.952 us; speedup vs baseline: 4.1018x; 4.1018x over previous
//
#include <hip/hip_runtime.h>
#include <hip/hip_bf16.h>

#define Nn 50000
#define Ee 1600000
#define Ff 64
#define Rr 5
#define Bb 4
#define Ll 4
#define Kk 2048
#define Mseg (Rr*Nn)     // 250000 segments, rel-major: seg = r*Nn + dst
#define NT ((Nn+63)/64)  // 782 node tiles
#define SVP 68

// ---- bf16 pack/unpack helpers (storage bf16, math fp32) ----
static __device__ __forceinline__ unsigned short f2b(float f){
  unsigned u = __float_as_uint(f);
  unsigned r = (u + 0x7fffu + ((u>>16)&1u)) >> 16;   // RTN-even
  return (unsigned short)r;
}
static __device__ __forceinline__ unsigned packbf(float lo, float hi){
  return (unsigned)f2b(lo) | ((unsigned)f2b(hi) << 16);
}
static __device__ __forceinline__ float2 unpackbf(unsigned u){
  return make_float2(__uint_as_float(u << 16), __uint_as_float(u & 0xffff0000u));
}

__global__ __launch_bounds__(256) void k_inv_init(int* __restrict__ inv){
  int i = blockIdx.x*256+threadIdx.x;
  if (i < Nn) inv[i] = -1;
}

__global__ __launch_bounds__(256) void k_inv_set(const int* __restrict__ tidx, int* __restrict__ inv,
                                                 int* __restrict__ tflag){
  int k = blockIdx.x*256+threadIdx.x;
  if (k < Kk){
    int n = tidx[k];
    inv[n] = k;
    tflag[n >> 6] = 1;   // benign race
  }
}

// x fp32 [N,64] -> packed bf16 pairs [N,32]
__global__ __launch_bounds__(256) void k_x2b(const float* __restrict__ x, unsigned* __restrict__ xb){
  int idx = blockIdx.x*256+threadIdx.x;
  if (idx < Nn*32){
    int n = idx >> 5, j = idx & 31;
    float2 v = *(const float2*)&x[(size_t)n*64 + 2*j];
    xb[idx] = packbf(v.x, v.y);
  }
}

__global__ __launch_bounds__(256) void k_cnt2(const int* __restrict__ ei, const int* __restrict__ et,
                                              int* __restrict__ cnt2){
  int e = blockIdx.x*256+threadIdx.x;
  if (e < Ee){
    int dst = ei[Ee + e];
    int r = et[e];
    atomicAdd(&cnt2[r*Nn + dst], 1);
  }
}

__global__ __launch_bounds__(256) void k_scan_blk(const int* __restrict__ cnt2, int* __restrict__ part,
                                                  int* __restrict__ bsum){
  __shared__ int s[256];
  int t = threadIdx.x; int idx = blockIdx.x*256+t;
  int v = (idx < Mseg) ? cnt2[idx] : 0;
  s[t] = v; __syncthreads();
  #pragma unroll
  for (int off=1; off<256; off<<=1){
    int x = (t>=off) ? s[t-off] : 0;
    __syncthreads();
    s[t] += x;
    __syncthreads();
  }
  if (idx < Mseg) part[idx] = s[t] - v;
  if (t == 255) bsum[blockIdx.x] = s[255];
}

__global__ __launch_bounds__(1024) void k_scan_top(int* __restrict__ bsum, int nb){
  __shared__ int s[1024];
  int t = threadIdx.x;
  int v = (t < nb) ? bsum[t] : 0;
  s[t] = v; __syncthreads();
  #pragma unroll
  for (int off=1; off<1024; off<<=1){
    int x = (t>=off) ? s[t-off] : 0;
    __syncthreads();
    s[t] += x;
    __syncthreads();
  }
  if (t < nb) bsum[t] = s[t] - v;
}

__global__ __launch_bounds__(256) void k_scan_add(const int* __restrict__ part, const int* __restrict__ bsum,
                                                  int* __restrict__ rowptr){
  int idx = blockIdx.x*256+threadIdx.x;
  if (idx < Mseg) rowptr[idx] = part[idx] + bsum[idx>>8];
  if (idx == 0) rowptr[Mseg] = Ee;
}

__global__ __launch_bounds__(256) void k_place(const int* __restrict__ ei, const int* __restrict__ et,
                                               const int* __restrict__ rowptr, int* __restrict__ fill,
                                               unsigned short* __restrict__ srcs){
  int e = blockIdx.x*256+threadIdx.x;
  if (e < Ee){
    int src = ei[e];
    int dst = ei[Ee + e];
    int r = et[e];
    int seg = r*Nn + dst;
    int pos = rowptr[seg] + atomicAdd(&fill[seg], 1);
    srcs[pos] = (unsigned short)src;
  }
}

// Wall: 384x64 fp32. rows 0..319 = W_r, rows 320..383 = root.
__global__ __launch_bounds__(256) void k_wall(const float* __restrict__ bases, const float* __restrict__ comps,
                                              const float* __restrict__ roots, float* __restrict__ Wall){
  int idx = blockIdx.x*256+threadIdx.x;
  if (idx >= 384*64) return;
  int o = idx & 63, row = idx >> 6;
  float s;
  if (row < 320){
    int r = row >> 6, i = row & 63;
    s = 0.f;
    #pragma unroll
    for (int b=0;b<Bb;b++)
      s += comps[r*Bb+b] * bases[(b*Ff + i)*Ff + o];
  } else {
    int i = row - 320;
    s = roots[i*Ff + o];
  }
  Wall[idx] = s;
}

// ---- segment mean body: half-wave (32 lanes) per segment; uint = 2 bf16 feats ----
static __device__ __forceinline__ void seg_body(int sid, int l2,
    const unsigned short* __restrict__ srcs, const int* __restrict__ rowptr,
    const unsigned* __restrict__ h2, unsigned* __restrict__ y2)
{
  int s = rowptr[sid], e = rowptr[sid+1];
  float a0 = 0.f, a1 = 0.f;
  int i = s;
  for (; i+4 <= e; i+=4){
    int s0 = srcs[i+0], s1 = srcs[i+1], s2 = srcs[i+2], s3 = srcs[i+3];
    unsigned u0 = h2[s0*32 + l2];
    unsigned u1 = h2[s1*32 + l2];
    unsigned u2 = h2[s2*32 + l2];
    unsigned u3 = h2[s3*32 + l2];
    float2 f0 = unpackbf(u0), f1 = unpackbf(u1), f2 = unpackbf(u2), f3 = unpackbf(u3);
    a0 += (f0.x + f1.x) + (f2.x + f3.x);
    a1 += (f0.y + f1.y) + (f2.y + f3.y);
  }
  for (; i<e; i++){
    float2 f = unpackbf(h2[srcs[i]*32 + l2]);
    a0 += f.x; a1 += f.y;
  }
  int cc = e - s;
  float sc = (cc > 0) ? 1.0f/(float)cc : 0.f;
  y2[(size_t)sid*32 + l2] = packbf(a0*sc, a1*sc);
}

// all segments (layers 0..2)
__global__ __launch_bounds__(256) void k_seg(const unsigned short* __restrict__ srcs,
    const int* __restrict__ rowptr, const unsigned* __restrict__ h2, unsigned* __restrict__ y2)
{
  int sid = blockIdx.x*8 + (threadIdx.x >> 5);
  if (sid >= Mseg) return;
  seg_body(sid, threadIdx.x & 31, srcs, rowptr, h2, y2);
}

// target segments only (layer 3): idx -> (c = idx>>11, k = idx&2047)
__global__ __launch_bounds__(256) void k_seg_t(const unsigned short* __restrict__ srcs,
    const int* __restrict__ rowptr, const unsigned* __restrict__ h2, unsigned* __restrict__ y2,
    const int* __restrict__ tidx)
{
  int idx = blockIdx.x*8 + (threadIdx.x >> 5);
  if (idx >= Rr*Kk) return;
  int c = idx >> 11;           // Kk == 2048
  int k = idx & (Kk-1);
  int sid = c*Nn + tidx[k];
  seg_body(sid, threadIdx.x & 31, srcs, rowptr, h2, y2);
}

// Combine: block = 64 nodes x 64 outputs; c-loop over 5 rel means + root.
// Register prefetch of next c tile (8 uints/thread) overlaps global latency with matmul.
__global__ __launch_bounds__(256) void k_comb(const unsigned* __restrict__ y2, const unsigned* __restrict__ h2,
    const float* __restrict__ Wall, const float* __restrict__ bias,
    unsigned* __restrict__ hn2, const int* __restrict__ inv, float* __restrict__ sel,
    int layer, const int* __restrict__ tflag)
{
  if (layer == Ll-1 && tflag[blockIdx.x] == 0) return;
  __shared__ __align__(16) float sW[64*64];
  __shared__ __align__(16) float sV[64*SVP];
  int t = threadIdx.x;
  int n0 = blockIdx.x*64;
  int nlim = Nn - n0; if (nlim > 64) nlim = 64;
  int oq = (t & 15)*4, nq = (t >> 4)*4;
  float4 acc[4];
  #pragma unroll
  for (int j=0;j<4;j++) acc[j] = make_float4(0.f,0.f,0.f,0.f);

  unsigned pf[8];
  auto fetch = [&](int c){
    #pragma unroll
    for (int q=0;q<8;q++){
      int lin = q*256 + t;
      int nl = lin >> 5, j = lin & 31;
      unsigned v = 0;
      if (nl < nlim)
        v = (c < 5) ? y2[((size_t)(c*Nn + n0 + nl))*32 + j]
                    : h2[(size_t)(n0 + nl)*32 + j];
      pf[q] = v;
    }
  };

  fetch(0);
  for (int c=0;c<6;c++){
    __syncthreads();   // prev matmul done reading sV (no-op cost at c=0)
    // unpack prefetched tile -> sV
    #pragma unroll
    for (int q=0;q<8;q++){
      int lin = q*256 + t;
      int nl = lin >> 5, j = lin & 31;
      float2 f = unpackbf(pf[q]);
      *(float2*)&sV[nl*SVP + 2*j] = f;
    }
    // stage W_c
    #pragma unroll
    for (int idx=t; idx<1024; idx+=256)
      *(float4*)&sW[idx*4] = *(const float4*)&Wall[c*4096 + idx*4];
    __syncthreads();
    if (c < 5) fetch(c+1);   // overlaps with matmul below
    #pragma unroll
    for (int i=0;i<64;i+=4){
      float4 v0 = *(const float4*)&sV[(nq+0)*SVP + i];
      float4 v1 = *(const float4*)&sV[(nq+1)*SVP + i];
      float4 v2 = *(const float4*)&sV[(nq+2)*SVP + i];
      float4 v3 = *(const float4*)&sV[(nq+3)*SVP + i];
      float4 w0 = *(const float4*)&sW[(i+0)*64 + oq];
      float4 w1 = *(const float4*)&sW[(i+1)*64 + oq];
      float4 w2 = *(const float4*)&sW[(i+2)*64 + oq];
      float4 w3 = *(const float4*)&sW[(i+3)*64 + oq];
      #define FMA4(A, V) \
        A.x += V.x*w0.x + V.y*w1.x + V.z*w2.x + V.w*w3.x; \
        A.y += V.x*w0.y + V.y*w1.y + V.z*w2.y + V.w*w3.y; \
        A.z += V.x*w0.z + V.y*w1.z + V.z*w2.z + V.w*w3.z; \
        A.w += V.x*w0.w + V.y*w1.w + V.z*w2.w + V.w*w3.w;
      FMA4(acc[0], v0)
      FMA4(acc[1], v1)
      FMA4(acc[2], v2)
      FMA4(acc[3], v3)
      #undef FMA4
    }
  }

  float4 bb = *(const float4*)&bias[oq];
  #pragma unroll
  for (int j=0;j<4;j++){
    int n = n0 + nq + j;
    if (n < Nn){
      float4 r;
      r.x = tanhf(acc[j].x + bb.x);
      r.y = tanhf(acc[j].y + bb.y);
      r.z = tanhf(acc[j].z + bb.z);
      r.w = tanhf(acc[j].w + bb.w);
      if (layer != Ll-1){
        uint2 p;
        p.x = packbf(r.x, r.y);
        p.y = packbf(r.z, r.w);
        *(uint2*)&hn2[(size_t)n*32 + (oq>>1)] = p;
      }
      int k = inv[n];
      if (k >= 0) *(float4*)&sel[(size_t)k*256 + layer*64 + oq] = r;
    }
  }
}

__global__ __launch_bounds__(256) void k_w1eff(const float* __restrict__ w1, float* __restrict__ w1e){
  int idx = blockIdx.x*256+threadIdx.x;
  if (idx < 256*128){
    int i = idx >> 7, j = idx & 127;
    w1e[idx] = w1[i*128 + j] + w1[(i+256)*128 + j];
  }
}

__global__ __launch_bounds__(128) void k_mlp(const float* __restrict__ sel, const float* __restrict__ w1e,
    const float* __restrict__ b1, const float* __restrict__ w2, const float* __restrict__ b2,
    float* __restrict__ out)
{
  __shared__ float sfeat[256];
  __shared__ float partial[2];
  int k = blockIdx.x, j = threadIdx.x;
  for (int idx=j; idx<256; idx+=128) sfeat[idx] = sel[(size_t)k*256 + idx];
  __syncthreads();
  float a = b1[j];
  for (int i=0;i<256;i++) a += sfeat[i] * w1e[i*128 + j];
  a = fmaxf(a, 0.f);
  float v = a * w2[j];
  #pragma unroll
  for (int off=32; off>0; off>>=1) v += __shfl_down(v, off, 64);
  if ((j & 63) == 0) partial[j>>6] = v;
  __syncthreads();
  if (j == 0) out[k] = partial[0] + partial[1] + b2[0];
}

extern "C" void kernel_launch(void* const* d_in, const int* in_sizes, int n_in,
                              void* d_out, int out_size, void* d_ws, size_t ws_size,
                              hipStream_t stream){
  const float* x     = (const float*)d_in[0];
  const int*  ei     = (const int*)d_in[1];
  const int*  et     = (const int*)d_in[2];
  const int*  tidx   = (const int*)d_in[3];
  const float* bases = (const float*)d_in[4];
  const float* comps = (const float*)d_in[5];
  const float* roots = (const float*)d_in[6];
  const float* biases= (const float*)d_in[7];
  const float* w1    = (const float*)d_in[8];
  const float* b1    = (const float*)d_in[9];
  const float* w2    = (const float*)d_in[10];
  const float* b2    = (const float*)d_in[11];
  float* out = (float*)d_out;

  char* wsp = (char*)d_ws;
  size_t off = 0;
  auto alloc = [&](size_t bytes)->void*{ void* p = wsp + off; off += (bytes + 255) & ~size_t(255); return p; };
  unsigned* xb    = (unsigned*)alloc(sizeof(unsigned)*(size_t)Nn*32);   // 6.4 MB
  unsigned* hA    = (unsigned*)alloc(sizeof(unsigned)*(size_t)Nn*32);   // 6.4 MB
  unsigned* hB    = (unsigned*)alloc(sizeof(unsigned)*(size_t)Nn*32);   // 6.4 MB
  unsigned* y2    = (unsigned*)alloc(sizeof(unsigned)*(size_t)Mseg*32); // 32 MB
  int*      cnt2  = (int*)  alloc(sizeof(int)*(Mseg));
  int*      part  = (int*)  alloc(sizeof(int)*(Mseg));
  int*      bsum  = (int*)  alloc(sizeof(int)*1024);
  int*      rowptr= (int*)  alloc(sizeof(int)*(Mseg+1));
  int*      fill  = (int*)  alloc(sizeof(int)*(Mseg));
  unsigned short* srcs = (unsigned short*)alloc(sizeof(unsigned short)*(size_t)Ee); // 3.2 MB
  float*    Wall  = (float*)alloc(sizeof(float)*384*64);
  float*    sel   = (float*)alloc(sizeof(float)*(size_t)Kk*256);        // 2 MB
  float*    w1e   = (float*)alloc(sizeof(float)*256*128);
  int*      inv   = (int*)  alloc(sizeof(int)*(size_t)Nn);
  int*      tflag = (int*)  alloc(sizeof(int)*NT);
  (void)ws_size;

  const int NB = (Mseg + 255)/256;   // 977 scan blocks

  hipMemsetAsync(cnt2, 0, sizeof(int)*Mseg, stream);
  hipMemsetAsync(fill, 0, sizeof(int)*Mseg, stream);
  hipMemsetAsync(tflag, 0, sizeof(int)*NT, stream);
  k_inv_init<<<(Nn+255)/256, 256, 0, stream>>>(inv);
  k_inv_set<<<(Kk+255)/256, 256, 0, stream>>>(tidx, inv, tflag);
  k_x2b<<<(Nn*32+255)/256, 256, 0, stream>>>(x, xb);
  k_w1eff<<<(256*128+255)/256, 256, 0, stream>>>(w1, w1e);
  k_cnt2<<<(Ee+255)/256, 256, 0, stream>>>(ei, et, cnt2);
  k_scan_blk<<<NB, 256, 0, stream>>>(cnt2, part, bsum);
  k_scan_top<<<1, 1024, 0, stream>>>(bsum, NB);
  k_scan_add<<<NB, 256, 0, stream>>>(part, bsum, rowptr);
  k_place<<<(Ee+255)/256, 256, 0, stream>>>(ei, et, rowptr, fill, srcs);

  const unsigned* hc = xb;
  unsigned* hn = hA;
  for (int l=0;l<Ll;l++){
    k_wall<<<(384*64+255)/256, 256, 0, stream>>>(bases + (size_t)l*Bb*Ff*Ff, comps + (size_t)l*Rr*Bb,
                                                 roots + (size_t)l*Ff*Ff, Wall);
    if (l < Ll-1)
      k_seg<<<(Mseg+7)/8, 256, 0, stream>>>(srcs, rowptr, hc, y2);
    else
      k_seg_t<<<(Rr*Kk)/8, 256, 0, stream>>>(srcs, rowptr, hc, y2, tidx);
    k_comb<<<NT, 256, 0, stream>>>(y2, hc, Wall, biases + (size_t)l*Ff, hn, inv, sel, l, tflag);
    hc = hn;
    hn = (hn == hA) ? hB : hA;
  }
  k_mlp<<<Kk, 128, 0, stream>>>(sel, w1e, b1, w2, b2, out);
}

// Round 8
// 503.300 us; speedup vs baseline: 6.5847x; 1.6053x over previous
//
#include <hip/hip_runtime.h>
#include <hip/hip_bf16.h>

#define Nn 50000
#define Ee 1600000
#define Ff 64
#define Rr 5
#define Bb 4
#define Ll 4
#define Kk 2048
#define Mseg (Rr*Nn)       // 250000 segments, rel-major: seg = r*Nn + dst
#define NT2 ((Nn+127)/128) // 391 row tiles of 128
#define WTP 392            // padded K stride (ushorts) for W^T

typedef __attribute__((ext_vector_type(8))) short short8;
typedef __attribute__((ext_vector_type(4))) float v4f;

// ---- bf16 pack/unpack helpers (storage bf16, math fp32) ----
static __device__ __forceinline__ unsigned short f2b(float f){
  unsigned u = __float_as_uint(f);
  unsigned r = (u + 0x7fffu + ((u>>16)&1u)) >> 16;   // RTN-even
  return (unsigned short)r;
}
static __device__ __forceinline__ unsigned packbf(float lo, float hi){
  return (unsigned)f2b(lo) | ((unsigned)f2b(hi) << 16);
}
static __device__ __forceinline__ float2 unpackbf(unsigned u){
  return make_float2(__uint_as_float(u << 16), __uint_as_float(u & 0xffff0000u));
}

__global__ __launch_bounds__(256) void k_inv_init(int* __restrict__ inv){
  int i = blockIdx.x*256+threadIdx.x;
  if (i < Nn) inv[i] = -1;
}

__global__ __launch_bounds__(256) void k_inv_set(const int* __restrict__ tidx, int* __restrict__ inv,
                                                 int* __restrict__ tflag){
  int k = blockIdx.x*256+threadIdx.x;
  if (k < Kk){
    int n = tidx[k];
    inv[n] = k;
    tflag[n >> 7] = 1;   // benign race; 128-row tiles
  }
}

// x fp32 [N,64] -> packed bf16 pairs [N,32]
__global__ __launch_bounds__(256) void k_x2b(const float* __restrict__ x, unsigned* __restrict__ xb){
  int idx = blockIdx.x*256+threadIdx.x;
  if (idx < Nn*32){
    int n = idx >> 5, j = idx & 31;
    float2 v = *(const float2*)&x[(size_t)n*64 + 2*j];
    xb[idx] = packbf(v.x, v.y);
  }
}

__global__ __launch_bounds__(256) void k_cnt2(const int* __restrict__ ei, const int* __restrict__ et,
                                              int* __restrict__ cnt2){
  int e = blockIdx.x*256+threadIdx.x;
  if (e < Ee){
    int dst = ei[Ee + e];
    int r = et[e];
    atomicAdd(&cnt2[r*Nn + dst], 1);
  }
}

__global__ __launch_bounds__(256) void k_scan_blk(const int* __restrict__ cnt2, int* __restrict__ part,
                                                  int* __restrict__ bsum){
  __shared__ int s[256];
  int t = threadIdx.x; int idx = blockIdx.x*256+t;
  int v = (idx < Mseg) ? cnt2[idx] : 0;
  s[t] = v; __syncthreads();
  #pragma unroll
  for (int off=1; off<256; off<<=1){
    int x = (t>=off) ? s[t-off] : 0;
    __syncthreads();
    s[t] += x;
    __syncthreads();
  }
  if (idx < Mseg) part[idx] = s[t] - v;
  if (t == 255) bsum[blockIdx.x] = s[255];
}

__global__ __launch_bounds__(1024) void k_scan_top(int* __restrict__ bsum, int nb){
  __shared__ int s[1024];
  int t = threadIdx.x;
  int v = (t < nb) ? bsum[t] : 0;
  s[t] = v; __syncthreads();
  #pragma unroll
  for (int off=1; off<1024; off<<=1){
    int x = (t>=off) ? s[t-off] : 0;
    __syncthreads();
    s[t] += x;
    __syncthreads();
  }
  if (t < nb) bsum[t] = s[t] - v;
}

__global__ __launch_bounds__(256) void k_scan_add(const int* __restrict__ part, const int* __restrict__ bsum,
                                                  int* __restrict__ rowptr){
  int idx = blockIdx.x*256+threadIdx.x;
  if (idx < Mseg) rowptr[idx] = part[idx] + bsum[idx>>8];
  if (idx == 0) rowptr[Mseg] = Ee;
}

__global__ __launch_bounds__(256) void k_place(const int* __restrict__ ei, const int* __restrict__ et,
                                               const int* __restrict__ rowptr, int* __restrict__ fill,
                                               unsigned short* __restrict__ srcs){
  int e = blockIdx.x*256+threadIdx.x;
  if (e < Ee){
    int src = ei[e];
    int dst = ei[Ee + e];
    int r = et[e];
    int seg = r*Nn + dst;
    int pos = rowptr[seg] + atomicAdd(&fill[seg], 1);
    srcs[pos] = (unsigned short)src;
  }
}

// W^T bf16 [64 out][392 pad] : k<320 -> W_{k/64}[k%64][o], k in 320..383 -> root[k-320][o]
__global__ __launch_bounds__(384) void k_wallT(const float* __restrict__ bases, const float* __restrict__ comps,
                                               const float* __restrict__ roots, unsigned short* __restrict__ WT){
  int o = blockIdx.x;          // 0..63
  int k = threadIdx.x;         // 0..383
  int c = k >> 6, i = k & 63;
  float s;
  if (c < 5){
    s = 0.f;
    #pragma unroll
    for (int b=0;b<Bb;b++)
      s += comps[c*Bb+b] * bases[(b*Ff + i)*Ff + o];
  } else {
    s = roots[i*Ff + o];
  }
  WT[o*WTP + k] = f2b(s);
}

// ---- segment mean body: half-wave (32 lanes) per segment; uint = 2 bf16 feats ----
static __device__ __forceinline__ void seg_body(int sid, int l2,
    const unsigned short* __restrict__ srcs, const int* __restrict__ rowptr,
    const unsigned* __restrict__ h2, unsigned* __restrict__ y2)
{
  int s = rowptr[sid], e = rowptr[sid+1];
  float a0 = 0.f, a1 = 0.f;
  int i = s;
  for (; i+4 <= e; i+=4){
    int s0 = srcs[i+0], s1 = srcs[i+1], s2 = srcs[i+2], s3 = srcs[i+3];
    unsigned u0 = h2[s0*32 + l2];
    unsigned u1 = h2[s1*32 + l2];
    unsigned u2 = h2[s2*32 + l2];
    unsigned u3 = h2[s3*32 + l2];
    float2 f0 = unpackbf(u0), f1 = unpackbf(u1), f2 = unpackbf(u2), f3 = unpackbf(u3);
    a0 += (f0.x + f1.x) + (f2.x + f3.x);
    a1 += (f0.y + f1.y) + (f2.y + f3.y);
  }
  for (; i<e; i++){
    float2 f = unpackbf(h2[srcs[i]*32 + l2]);
    a0 += f.x; a1 += f.y;
  }
  int cc = e - s;
  float sc = (cc > 0) ? 1.0f/(float)cc : 0.f;
  y2[(size_t)sid*32 + l2] = packbf(a0*sc, a1*sc);
}

__global__ __launch_bounds__(256) void k_seg(const unsigned short* __restrict__ srcs,
    const int* __restrict__ rowptr, const unsigned* __restrict__ h2, unsigned* __restrict__ y2)
{
  int sid = blockIdx.x*8 + (threadIdx.x >> 5);
  if (sid >= Mseg) return;
  seg_body(sid, threadIdx.x & 31, srcs, rowptr, h2, y2);
}

__global__ __launch_bounds__(256) void k_seg_t(const unsigned short* __restrict__ srcs,
    const int* __restrict__ rowptr, const unsigned* __restrict__ h2, unsigned* __restrict__ y2,
    const int* __restrict__ tidx)
{
  int idx = blockIdx.x*8 + (threadIdx.x >> 5);
  if (idx >= Rr*Kk) return;
  int c = idx >> 11;           // Kk == 2048
  int k = idx & (Kk-1);
  int sid = c*Nn + tidx[k];
  seg_body(sid, threadIdx.x & 31, srcs, rowptr, h2, y2);
}

// MFMA combine: [N,384]@[384,64]. Block = 512 thr (8 waves) x 128 rows.
// A-frags load directly from y2/h2 (global, coalesced dwordx4); B = W^T bf16 from LDS.
__global__ __launch_bounds__(512) void k_combm(const unsigned* __restrict__ y2, const unsigned* __restrict__ h2,
    const unsigned short* __restrict__ WT, const float* __restrict__ bias,
    unsigned short* __restrict__ hn, const int* __restrict__ inv, float* __restrict__ sel,
    int layer, const int* __restrict__ tflag)
{
  if (layer == Ll-1 && tflag[blockIdx.x] == 0) return;
  __shared__ unsigned short sWT[64*WTP];   // 50176 B
  {
    const unsigned* srcw = (const unsigned*)WT;
    unsigned* dstw = (unsigned*)sWT;
    for (int i = threadIdx.x; i < 64*WTP/2; i += 512) dstw[i] = srcw[i];
  }
  __syncthreads();

  int wv = threadIdx.x >> 6, lane = threadIdx.x & 63;
  int m = lane & 15, q = lane >> 4;
  int row = blockIdx.x*128 + wv*16 + m;
  int rowc = (row < Nn) ? row : Nn-1;      // clamp loads
  const char* y2c = (const char*)y2;
  const char* h2c = (const char*)h2;

  v4f acc0 = {0.f,0.f,0.f,0.f}, acc1 = {0.f,0.f,0.f,0.f},
      acc2 = {0.f,0.f,0.f,0.f}, acc3 = {0.f,0.f,0.f,0.f};

  #pragma unroll
  for (int kk=0; kk<12; kk++){
    const char* base = (kk < 10)
      ? y2c + ((size_t)((kk>>1)*Nn + rowc))*128 + (size_t)(kk&1)*64
      : h2c + ((size_t)rowc)*128 + (size_t)(kk&1)*64;
    short8 a = *(const short8*)(base + q*16);
    const unsigned short* wb = &sWT[m*WTP + kk*32 + q*8];
    short8 b0 = *(const short8*)(wb);
    short8 b1 = *(const short8*)(wb + 16*WTP);
    short8 b2 = *(const short8*)(wb + 32*WTP);
    short8 b3 = *(const short8*)(wb + 48*WTP);
    acc0 = __builtin_amdgcn_mfma_f32_16x16x32_bf16(a, b0, acc0, 0, 0, 0);
    acc1 = __builtin_amdgcn_mfma_f32_16x16x32_bf16(a, b1, acc1, 0, 0, 0);
    acc2 = __builtin_amdgcn_mfma_f32_16x16x32_bf16(a, b2, acc2, 0, 0, 0);
    acc3 = __builtin_amdgcn_mfma_f32_16x16x32_bf16(a, b3, acc3, 0, 0, 0);
  }

  // epilogue: C/D layout col=lane&15, row=q*4+reg
  float bc0 = bias[ 0 + m], bc1 = bias[16 + m], bc2 = bias[32 + m], bc3 = bias[48 + m];
  #pragma unroll
  for (int j=0;j<4;j++){
    int node = blockIdx.x*128 + wv*16 + q*4 + j;
    if (node < Nn){
      float r0 = tanhf(acc0[j] + bc0);
      float r1 = tanhf(acc1[j] + bc1);
      float r2 = tanhf(acc2[j] + bc2);
      float r3 = tanhf(acc3[j] + bc3);
      if (layer != Ll-1){
        unsigned short* hp = &hn[(size_t)node*64];
        hp[ 0 + m] = f2b(r0);
        hp[16 + m] = f2b(r1);
        hp[32 + m] = f2b(r2);
        hp[48 + m] = f2b(r3);
      }
      int k = inv[node];
      if (k >= 0){
        float* sp = &sel[(size_t)k*256 + layer*64];
        sp[ 0 + m] = r0;
        sp[16 + m] = r1;
        sp[32 + m] = r2;
        sp[48 + m] = r3;
      }
    }
  }
}

__global__ __launch_bounds__(256) void k_w1eff(const float* __restrict__ w1, float* __restrict__ w1e){
  int idx = blockIdx.x*256+threadIdx.x;
  if (idx < 256*128){
    int i = idx >> 7, j = idx & 127;
    w1e[idx] = w1[i*128 + j] + w1[(i+256)*128 + j];
  }
}

__global__ __launch_bounds__(128) void k_mlp(const float* __restrict__ sel, const float* __restrict__ w1e,
    const float* __restrict__ b1, const float* __restrict__ w2, const float* __restrict__ b2,
    float* __restrict__ out)
{
  __shared__ float sfeat[256];
  __shared__ float partial[2];
  int k = blockIdx.x, j = threadIdx.x;
  for (int idx=j; idx<256; idx+=128) sfeat[idx] = sel[(size_t)k*256 + idx];
  __syncthreads();
  float a = b1[j];
  for (int i=0;i<256;i++) a += sfeat[i] * w1e[i*128 + j];
  a = fmaxf(a, 0.f);
  float v = a * w2[j];
  #pragma unroll
  for (int off=32; off>0; off>>=1) v += __shfl_down(v, off, 64);
  if ((j & 63) == 0) partial[j>>6] = v;
  __syncthreads();
  if (j == 0) out[k] = partial[0] + partial[1] + b2[0];
}

extern "C" void kernel_launch(void* const* d_in, const int* in_sizes, int n_in,
                              void* d_out, int out_size, void* d_ws, size_t ws_size,
                              hipStream_t stream){
  const float* x     = (const float*)d_in[0];
  const int*  ei     = (const int*)d_in[1];
  const int*  et     = (const int*)d_in[2];
  const int*  tidx   = (const int*)d_in[3];
  const float* bases = (const float*)d_in[4];
  const float* comps = (const float*)d_in[5];
  const float* roots = (const float*)d_in[6];
  const float* biases= (const float*)d_in[7];
  const float* w1    = (const float*)d_in[8];
  const float* b1    = (const float*)d_in[9];
  const float* w2    = (const float*)d_in[10];
  const float* b2    = (const float*)d_in[11];
  float* out = (float*)d_out;

  char* wsp = (char*)d_ws;
  size_t off = 0;
  auto alloc = [&](size_t bytes)->void*{ void* p = wsp + off; off += (bytes + 255) & ~size_t(255); return p; };
  unsigned* xb    = (unsigned*)alloc(sizeof(unsigned)*(size_t)Nn*32);   // 6.4 MB
  unsigned* hA    = (unsigned*)alloc(sizeof(unsigned)*(size_t)Nn*32);   // 6.4 MB
  unsigned* hB    = (unsigned*)alloc(sizeof(unsigned)*(size_t)Nn*32);   // 6.4 MB
  unsigned* y2    = (unsigned*)alloc(sizeof(unsigned)*(size_t)Mseg*32); // 32 MB
  int*      cnt2  = (int*)  alloc(sizeof(int)*(Mseg));
  int*      part  = (int*)  alloc(sizeof(int)*(Mseg));
  int*      bsum  = (int*)  alloc(sizeof(int)*1024);
  int*      rowptr= (int*)  alloc(sizeof(int)*(Mseg+1));
  int*      fill  = (int*)  alloc(sizeof(int)*(Mseg));
  unsigned short* srcs = (unsigned short*)alloc(sizeof(unsigned short)*(size_t)Ee); // 3.2 MB
  unsigned short* WT   = (unsigned short*)alloc(sizeof(unsigned short)*64*WTP);
  float*    sel   = (float*)alloc(sizeof(float)*(size_t)Kk*256);        // 2 MB
  float*    w1e   = (float*)alloc(sizeof(float)*256*128);
  int*      inv   = (int*)  alloc(sizeof(int)*(size_t)Nn);
  int*      tflag = (int*)  alloc(sizeof(int)*NT2);
  (void)ws_size;

  const int NB = (Mseg + 255)/256;   // 977 scan blocks

  hipMemsetAsync(cnt2, 0, sizeof(int)*Mseg, stream);
  hipMemsetAsync(fill, 0, sizeof(int)*Mseg, stream);
  hipMemsetAsync(tflag, 0, sizeof(int)*NT2, stream);
  k_inv_init<<<(Nn+255)/256, 256, 0, stream>>>(inv);
  k_inv_set<<<(Kk+255)/256, 256, 0, stream>>>(tidx, inv, tflag);
  k_x2b<<<(Nn*32+255)/256, 256, 0, stream>>>(x, xb);
  k_w1eff<<<(256*128+255)/256, 256, 0, stream>>>(w1, w1e);
  k_cnt2<<<(Ee+255)/256, 256, 0, stream>>>(ei, et, cnt2);
  k_scan_blk<<<NB, 256, 0, stream>>>(cnt2, part, bsum);
  k_scan_top<<<1, 1024, 0, stream>>>(bsum, NB);
  k_scan_add<<<NB, 256, 0, stream>>>(part, bsum, rowptr);
  k_place<<<(Ee+255)/256, 256, 0, stream>>>(ei, et, rowptr, fill, srcs);

  const unsigned* hc = xb;
  unsigned* hn = hA;
  for (int l=0;l<Ll;l++){
    k_wallT<<<64, 384, 0, stream>>>(bases + (size_t)l*Bb*Ff*Ff, comps + (size_t)l*Rr*Bb,
                                    roots + (size_t)l*Ff*Ff, WT);
    if (l < Ll-1)
      k_seg<<<(Mseg+7)/8, 256, 0, stream>>>(srcs, rowptr, hc, y2);
    else
      k_seg_t<<<(Rr*Kk)/8, 256, 0, stream>>>(srcs, rowptr, hc, y2, tidx);
    k_combm<<<NT2, 512, 0, stream>>>(y2, hc, WT, biases + (size_t)l*Ff,
                                     (unsigned short*)hn, inv, sel, l, tflag);
    hc = hn;
    hn = (hn == hA) ? hB : hA;
  }
  k_mlp<<<Kk, 128, 0, stream>>>(sel, w1e, b1, w2, b2, out);
}